// Round 10
// baseline (3894.205 us; speedup 1.0000x reference)
//
#include <hip/hip_runtime.h>
#include <math.h>

#define BD 16384            // B*D
#define TT 512
#define KDIM 1024
#define NDIM 1024
#define GEMM_M 8192
#define PANEL_Q 320         // OpenBLAS SGEMM_DEFAULT_Q (SKYLAKEX/COOPERLAKE AVX512 path)
#define LOGE2F 0.69314718246459960938f

// ===========================================================================
// Scan transcendentals: ROCm native f32 libm — FROZEN (r7/r8/r9 passed).
// Compound arithmetic uses __fadd_rn/__fmul_rn/__fsub_rn to forbid FMA
// contraction. All formulas bit-identical to r9.
// ===========================================================================
__device__ __forceinline__ float np_expf(float x)   { return expf(x); }
__device__ __forceinline__ float np_logf(float x)   { return logf(x); }
__device__ __forceinline__ float np_log1pf(float x) { return log1pf(x); }

__device__ __forceinline__ float np_softplus(float v) {
    const float e  = np_expf(-fabsf(v));
    const float l1 = np_log1pf(e);
    const float r  = __fadd_rn(fmaxf(v, 0.0f), l1);
    return (v == 0.0f) ? LOGE2F : r;      // npy_logaddexpf x==y special case
}

__device__ __forceinline__ void np_sla(float la, float sa, float lb, float sb,
                                       float& lo, float& so) {
    bool az = la <= -39.0f;                  // LOG_ZERO + 1
    bool bz = lb <= -39.0f;
    float mx = fmaxf(la, lb);
    float mn = fminf(la, lb);
    float diff = __fsub_rn(mn, mx);
    bool amax = la >= lb;
    float smax = amax ? sa : sb;
    float smin = amax ? sb : sa;
    bool same = __fmul_rn(smax, smin) > 0.0f;
    float ed = np_expf(diff);
    float ls  = __fadd_rn(mx, np_log1pf(ed));
    float lop = __fadd_rn(mx, np_log1pf(-fminf(ed, 0.9999f)));
    float l = same ? ls : lop;
    float s = smax;
    l = az ? lb : l;  s = az ? sb : s;
    bool bo = bz && !az;
    l = bo ? la : l;  s = bo ? sa : s;
    lo = l; so = s;
}

// ===========================================================================
// OpenBLAS-sgemm-exact NT-GEMM — FROZEN (r7-r9 passed): single-accumulator
// FMA chain, k ascending, Q=320 panels {320,320,320,64}, left-assoc fold,
// bias as separate f32 add. Tile 64x64, BK=16, 256 threads, 4x4 per thread.
// ===========================================================================
__global__ __launch_bounds__(256) void gemm_blas(
    const float* __restrict__ x,
    const float* __restrict__ Wa, const float* __restrict__ Wx, const float* __restrict__ Wd,
    const float* __restrict__ ba, const float* __restrict__ bx, const float* __restrict__ bd,
    float* __restrict__ out_a, float* __restrict__ out_x, float* __restrict__ out_d)
{
    const int z = blockIdx.z;
    const float* W    = (z == 0) ? Wa : (z == 1) ? Wx : Wd;
    const float* bias = (z == 0) ? ba : (z == 1) ? bx : bd;
    float* out        = (z == 0) ? out_a : (z == 1) ? out_x : out_d;

    const int m0 = blockIdx.x * 64;
    const int n0 = blockIdx.y * 64;

    __shared__ float As[16][68];   // [k in tile][m]
    __shared__ float Bs[16][68];   // [k in tile][n]

    const int tid = threadIdx.x;
    const int lr = tid >> 2;       // 0..63 staging row
    const int lc = tid & 3;        // float4 column
    const int ty = tid >> 4;       // 0..15 -> m = ty*4 + i
    const int tx = tid & 15;       // 0..15 -> n = tx*4 + j

    const float* Ap = x + (size_t)(m0 + lr) * KDIM + lc * 4;
    const float* Bp = W + (size_t)(n0 + lr) * KDIM + lc * 4;

    float4 fa = *(const float4*)Ap;
    float4 fb = *(const float4*)Bp;

    float tot[4][4];               // folded finished panels
    float acc[4][4];               // current panel FMA chain
    #pragma unroll
    for (int i = 0; i < 4; ++i)
        #pragma unroll
        for (int j = 0; j < 4; ++j) { tot[i][j] = 0.0f; acc[i][j] = 0.0f; }

    for (int kt = 0; kt < KDIM; kt += 16) {
        if (kt == PANEL_Q || kt == 2 * PANEL_Q || kt == 3 * PANEL_Q) {
            #pragma unroll
            for (int i = 0; i < 4; ++i)
                #pragma unroll
                for (int j = 0; j < 4; ++j) {
                    tot[i][j] = __fadd_rn(tot[i][j], acc[i][j]);  // C += panel
                    acc[i][j] = 0.0f;
                }
        }
        __syncthreads();
        {
            const float* pa = (const float*)&fa;
            const float* pb = (const float*)&fb;
            #pragma unroll
            for (int c = 0; c < 4; ++c) {
                As[lc * 4 + c][lr] = pa[c];
                Bs[lc * 4 + c][lr] = pb[c];
            }
        }
        __syncthreads();
        if (kt + 16 < KDIM) {
            fa = *(const float4*)(Ap + kt + 16);
            fb = *(const float4*)(Bp + kt + 16);
        }
        #pragma unroll
        for (int kk = 0; kk < 16; ++kk) {          // k strictly ascending
            const float4 a = *(const float4*)&As[kk][ty * 4];
            const float4 b = *(const float4*)&Bs[kk][tx * 4];
            const float av[4] = {a.x, a.y, a.z, a.w};
            const float bv[4] = {b.x, b.y, b.z, b.w};
            #pragma unroll
            for (int i = 0; i < 4; ++i)
                #pragma unroll
                for (int j = 0; j < 4; ++j)
                    acc[i][j] = __fmaf_rn(av[i], bv[j], acc[i][j]);
        }
    }
    #pragma unroll
    for (int i = 0; i < 4; ++i)                    // fold last (64-wide) panel
        #pragma unroll
        for (int j = 0; j < 4; ++j)
            tot[i][j] = __fadd_rn(tot[i][j], acc[i][j]);

    float bj[4];
    #pragma unroll
    for (int j = 0; j < 4; ++j) bj[j] = bias[n0 + tx * 4 + j];

    #pragma unroll
    for (int i = 0; i < 4; ++i) {
        float4 v;
        float* op = out + (size_t)(m0 + ty * 4 + i) * NDIM + n0 + tx * 4;
        v.x = __fadd_rn(tot[i][0], bj[0]);
        v.y = __fadd_rn(tot[i][1], bj[1]);
        v.z = __fadd_rn(tot[i][2], bj[2]);
        v.w = __fadd_rn(tot[i][3], bj[3]);
        *(float4*)op = v;
    }
}

// ===========================================================================
// f32 scan, T=512 as 128 groups of 4. TWO independent lanes per thread
// (idx and idx+8192 — same d, so shared lrh/srh): the two serial chains
// interleave in-wave, filling each other's dependent-latency bubbles.
// Double-buffered group prefetch (A/B), conditional-free steady state (tail
// prefetch clamps to group 127; values discarded). sched_barrier(0) pins
// each load batch. All per-lane arithmetic bit-identical to r9.
// ===========================================================================
#define NL 2               // lanes per thread
#define HBD 8192           // BD / NL

__global__ __launch_bounds__(64, 1) void scan_kernel(
    float* __restrict__ log_h, float* __restrict__ sign_h, float* __restrict__ h_lin,
    const float* __restrict__ log_r_h, const float* __restrict__ sign_r_h)
{
    const int idx0 = blockIdx.x * 64 + threadIdx.x;   // 0..8191
    const int d = idx0 & 1023;                         // same for both lanes
    const float lrh = log_r_h[d];
    const float srh = sign_r_h[d];

    float lhp[NL], shp[NL];
    #pragma unroll
    for (int c = 0; c < NL; ++c) {
        log_h[idx0 + c * HBD] = -40.0f;
        sign_h[idx0 + c * HBD] = 1.0f;
        lhp[c] = -40.0f;
        shp[c] = 1.0f;
    }

    float Aa[NL][4], Al[NL][4], Ad[NL][4];     // raw buffer A
    float Ba[NL][4], Bl[NL][4], Bd[NL][4];     // raw buffer B
    float Xa[NL][4], Xli[NL][4], Xsi[NL][4], Xld[NL][4], Xlm[NL][4];

#define LOADG(GG, Ra, Rl, Rd) do {                                       \
    const int _b = (GG) * 4;                                             \
    _Pragma("unroll")                                                    \
    for (int u = 0; u < 4; ++u) {                                        \
        _Pragma("unroll")                                                \
        for (int c = 0; c < NL; ++c) {                                   \
            const int _i = idx0 + c * HBD;                               \
            Ra[c][u] = h_lin[(_b + u) * BD + _i];                        \
            Rl[c][u] = log_h[(_b + u + 1) * BD + _i];                    \
            Rd[c][u] = sign_h[(_b + u + 1) * BD + _i];                   \
        }                                                                \
    } } while (0)

// xform: bit-identical per lane to r8/r9 (passed).
#define XFORM(Ra, Rl, Rd) do {                                           \
    _Pragma("unroll")                                                    \
    for (int u = 0; u < 4; ++u) {                                        \
        _Pragma("unroll")                                                \
        for (int c = 0; c < NL; ++c) {                                   \
            Xa[c][u] = __fadd_rn(1.0f, np_softplus(Ra[c][u]));           \
            const float ax = fabsf(Rl[c][u]);                            \
            Xli[c][u] = (ax > 1e-10f) ? np_logf(fmaxf(ax, 1e-10f))       \
                                      : -40.0f;                          \
            Xsi[c][u] = (Rl[c][u] < 0.0f) ? -1.0f : 1.0f;                \
            const float dr = Rd[c][u];                                   \
            const float e  = np_expf(-fabsf(dr));                        \
            const float l1 = np_log1pf(e);                               \
            const float big = -__fadd_rn(fabsf(dr), l1);                 \
            const float sml = -l1;                                       \
            const float ld0 = (dr > 0.0f) ? sml : big;                   \
            const float lm0 = (dr > 0.0f) ? big : sml;                   \
            Xld[c][u] = (dr == 0.0f) ? -LOGE2F : ld0;                    \
            Xlm[c][u] = (dr == 0.0f) ? -LOGE2F : lm0;                    \
        }                                                                \
    } } while (0)

// Serial chains: c-loop inside u-loop so the two dependent chains interleave.
#define SERIAL4(GG) do {                                                 \
    _Pragma("unroll")                                                    \
    for (int u = 0; u < 4; ++u) {                                        \
        const int t = (GG) * 4 + u;                                      \
        _Pragma("unroll")                                                \
        for (int c = 0; c < NL; ++c) {                                   \
            const int _i = idx0 + c * HBD;                               \
            const float log_rh  = __fadd_rn(lrh, lhp[c]);                \
            const float sign_rh = __fmul_rn(srh, shp[c]);                \
            float lv, sv;                                                \
            np_sla(log_rh, sign_rh, Xli[c][u], Xsi[c][u], lv, sv);       \
            const float tt = __fmul_rn(Xa[c][u], lv);                    \
            const float log_cand = -np_softplus(-tt);                    \
            float lhn, shn;                                              \
            np_sla(__fadd_rn(Xlm[c][u], lhp[c]), shp[c],                 \
                   __fadd_rn(Xld[c][u], log_cand), sv, lhn, shn);        \
            const float res = __fmul_rn(shn,                             \
                                        np_expf(fminf(lhn, 20.0f)));     \
            const float h = (lhn > -39.0f) ? res : 0.0f;                 \
            log_h[(t + 1) * BD + _i] = lhn;                              \
            sign_h[(t + 1) * BD + _i] = shn;                             \
            h_lin[t * BD + _i] = h;                                      \
            lhp[c] = lhn; shp[c] = shn;                                  \
        }                                                                \
    } } while (0)

    // Prologue: invariant at loop top — X=xform(g), B=raw(g+1), A=inflight(g+2)
    LOADG(0, Aa, Al, Ad);
    LOADG(1, Ba, Bl, Bd);
    XFORM(Aa, Al, Ad);                 // X = xform(group 0)
    LOADG(2, Aa, Al, Ad);              // A <- group 2 (in flight)
    __builtin_amdgcn_sched_barrier(0);

    for (int g = 0; g < 128; g += 2) {
        SERIAL4(g);                    // consume X = xform(g)
        XFORM(Ba, Bl, Bd);             // X = xform(g+1)
        { const int gg = (g + 3 < 128) ? g + 3 : 127;
          LOADG(gg, Ba, Bl, Bd); }     // B <- raw(g+3) in flight
        __builtin_amdgcn_sched_barrier(0);

        SERIAL4(g + 1);                // consume X = xform(g+1)
        XFORM(Aa, Al, Ad);             // X = xform(g+2)  (A arrived)
        { const int gg = (g + 4 < 128) ? g + 4 : 127;
          LOADG(gg, Aa, Al, Ad); }     // A <- raw(g+4) in flight
        __builtin_amdgcn_sched_barrier(0);
    }
#undef LOADG
#undef XFORM
#undef SERIAL4
}

// ===========================================================================
extern "C" void kernel_launch(void* const* d_in, const int* in_sizes, int n_in,
                              void* d_out, int out_size, void* d_ws, size_t ws_size,
                              hipStream_t stream) {
    const float* x        = (const float*)d_in[0];
    const float* W_x      = (const float*)d_in[1];
    const float* W_alpha  = (const float*)d_in[2];
    const float* W_delta  = (const float*)d_in[3];
    const float* b        = (const float*)d_in[4];
    const float* b_alpha  = (const float*)d_in[5];
    const float* b_delta  = (const float*)d_in[6];
    const float* log_r_h  = (const float*)d_in[7];
    const float* sign_r_h = (const float*)d_in[8];

    float* out    = (float*)d_out;
    float* log_h  = out;                            // [513, BD]
    float* sign_h = out + (size_t)513 * BD;         // [513, BD]
    float* h_lin  = out + (size_t)2 * 513 * BD;     // [512, BD]

    dim3 ggrid(GEMM_M / 64, NDIM / 64, 3);
    gemm_blas<<<ggrid, dim3(256), 0, stream>>>(
        x, W_alpha, W_x, W_delta, b_alpha, b, b_delta,
        h_lin, log_h + BD, sign_h + BD);

    scan_kernel<<<dim3(HBD / 64), dim3(64), 0, stream>>>(
        log_h, sign_h, h_lin, log_r_h, sign_r_h);
}

// Round 11
// 1614.280 us; speedup vs baseline: 2.4123x; 2.4123x over previous
//
#include <hip/hip_runtime.h>
#include <math.h>

#define BD 16384            // B*D
#define TT 512
#define KDIM 1024
#define NDIM 1024
#define GEMM_M 8192
#define PANEL_Q 320         // OpenBLAS SGEMM_DEFAULT_Q (SKYLAKEX/COOPERLAKE AVX512 path)
#define LOGE2F 0.69314718246459960938f

// ===========================================================================
// Scan transcendentals: ROCm native f32 libm — FROZEN (r7-r10 passed).
// Compound arithmetic uses __fadd_rn/__fmul_rn/__fsub_rn to forbid FMA
// contraction. All formulas bit-identical to r9.
// ===========================================================================
__device__ __forceinline__ float np_expf(float x)   { return expf(x); }
__device__ __forceinline__ float np_logf(float x)   { return logf(x); }
__device__ __forceinline__ float np_log1pf(float x) { return log1pf(x); }

__device__ __forceinline__ float np_softplus(float v) {
    const float e  = np_expf(-fabsf(v));
    const float l1 = np_log1pf(e);
    const float r  = __fadd_rn(fmaxf(v, 0.0f), l1);
    return (v == 0.0f) ? LOGE2F : r;      // npy_logaddexpf x==y special case
}

__device__ __forceinline__ void np_sla(float la, float sa, float lb, float sb,
                                       float& lo, float& so) {
    bool az = la <= -39.0f;                  // LOG_ZERO + 1
    bool bz = lb <= -39.0f;
    float mx = fmaxf(la, lb);
    float mn = fminf(la, lb);
    float diff = __fsub_rn(mn, mx);
    bool amax = la >= lb;
    float smax = amax ? sa : sb;
    float smin = amax ? sb : sa;
    bool same = __fmul_rn(smax, smin) > 0.0f;
    float ed = np_expf(diff);
    float ls  = __fadd_rn(mx, np_log1pf(ed));
    float lop = __fadd_rn(mx, np_log1pf(-fminf(ed, 0.9999f)));
    float l = same ? ls : lop;
    float s = smax;
    l = az ? lb : l;  s = az ? sb : s;
    bool bo = bz && !az;
    l = bo ? la : l;  s = bo ? sa : s;
    lo = l; so = s;
}

// ===========================================================================
// OpenBLAS-sgemm-exact NT-GEMM — FROZEN (r7-r10 passed): single-accumulator
// FMA chain, k ascending, Q=320 panels {320,320,320,64}, left-assoc fold,
// bias as separate f32 add. Tile 64x64, BK=16, 256 threads, 4x4 per thread.
// ===========================================================================
__global__ __launch_bounds__(256) void gemm_blas(
    const float* __restrict__ x,
    const float* __restrict__ Wa, const float* __restrict__ Wx, const float* __restrict__ Wd,
    const float* __restrict__ ba, const float* __restrict__ bx, const float* __restrict__ bd,
    float* __restrict__ out_a, float* __restrict__ out_x, float* __restrict__ out_d)
{
    const int z = blockIdx.z;
    const float* W    = (z == 0) ? Wa : (z == 1) ? Wx : Wd;
    const float* bias = (z == 0) ? ba : (z == 1) ? bx : bd;
    float* out        = (z == 0) ? out_a : (z == 1) ? out_x : out_d;

    const int m0 = blockIdx.x * 64;
    const int n0 = blockIdx.y * 64;

    __shared__ float As[16][68];   // [k in tile][m]
    __shared__ float Bs[16][68];   // [k in tile][n]

    const int tid = threadIdx.x;
    const int lr = tid >> 2;       // 0..63 staging row
    const int lc = tid & 3;        // float4 column
    const int ty = tid >> 4;       // 0..15 -> m = ty*4 + i
    const int tx = tid & 15;       // 0..15 -> n = tx*4 + j

    const float* Ap = x + (size_t)(m0 + lr) * KDIM + lc * 4;
    const float* Bp = W + (size_t)(n0 + lr) * KDIM + lc * 4;

    float4 fa = *(const float4*)Ap;
    float4 fb = *(const float4*)Bp;

    float tot[4][4];               // folded finished panels
    float acc[4][4];               // current panel FMA chain
    #pragma unroll
    for (int i = 0; i < 4; ++i)
        #pragma unroll
        for (int j = 0; j < 4; ++j) { tot[i][j] = 0.0f; acc[i][j] = 0.0f; }

    for (int kt = 0; kt < KDIM; kt += 16) {
        if (kt == PANEL_Q || kt == 2 * PANEL_Q || kt == 3 * PANEL_Q) {
            #pragma unroll
            for (int i = 0; i < 4; ++i)
                #pragma unroll
                for (int j = 0; j < 4; ++j) {
                    tot[i][j] = __fadd_rn(tot[i][j], acc[i][j]);  // C += panel
                    acc[i][j] = 0.0f;
                }
        }
        __syncthreads();
        {
            const float* pa = (const float*)&fa;
            const float* pb = (const float*)&fb;
            #pragma unroll
            for (int c = 0; c < 4; ++c) {
                As[lc * 4 + c][lr] = pa[c];
                Bs[lc * 4 + c][lr] = pb[c];
            }
        }
        __syncthreads();
        if (kt + 16 < KDIM) {
            fa = *(const float4*)(Ap + kt + 16);
            fb = *(const float4*)(Bp + kt + 16);
        }
        #pragma unroll
        for (int kk = 0; kk < 16; ++kk) {          // k strictly ascending
            const float4 a = *(const float4*)&As[kk][ty * 4];
            const float4 b = *(const float4*)&Bs[kk][tx * 4];
            const float av[4] = {a.x, a.y, a.z, a.w};
            const float bv[4] = {b.x, b.y, b.z, b.w};
            #pragma unroll
            for (int i = 0; i < 4; ++i)
                #pragma unroll
                for (int j = 0; j < 4; ++j)
                    acc[i][j] = __fmaf_rn(av[i], bv[j], acc[i][j]);
        }
    }
    #pragma unroll
    for (int i = 0; i < 4; ++i)                    // fold last (64-wide) panel
        #pragma unroll
        for (int j = 0; j < 4; ++j)
            tot[i][j] = __fadd_rn(tot[i][j], acc[i][j]);

    float bj[4];
    #pragma unroll
    for (int j = 0; j < 4; ++j) bj[j] = bias[n0 + tx * 4 + j];

    #pragma unroll
    for (int i = 0; i < 4; ++i) {
        float4 v;
        float* op = out + (size_t)(m0 + ty * 4 + i) * NDIM + n0 + tx * 4;
        v.x = __fadd_rn(tot[i][0], bj[0]);
        v.y = __fadd_rn(tot[i][1], bj[1]);
        v.z = __fadd_rn(tot[i][2], bj[2]);
        v.w = __fadd_rn(tot[i][3], bj[3]);
        *(float4*)op = v;
    }
}

// ===========================================================================
// f32 scan, T=512 as 128 groups of 4. ONE lane per thread (r9 mapping).
// Inputs stream global -> LDS via global_load_lds into a 4-slot ring
// (12 values x 64 lanes per group); consumption waits use HAND-COUNTED
// vmcnt so the wave NEVER waits on its own recent stores:
//   steady state FIFO (old->new): loads(g) | stores(g-1) | loads(g+1)
//   -> vmcnt(24) completes exactly loads(g).
// ds_read/lgkmcnt ordering is compiler-managed (normal __shared__ reads).
// All value-producing arithmetic bit-identical to r9.
// ===========================================================================
__device__ __forceinline__ void gl_lds(const float* g, float* l) {
    __builtin_amdgcn_global_load_lds(
        (const __attribute__((address_space(1))) void*)g,
        (__attribute__((address_space(3))) void*)l, 4, 0, 0);
}

#define WAITVM(N) do {                                                   \
    asm volatile("s_waitcnt vmcnt(" #N ")" ::: "memory");                \
    __builtin_amdgcn_sched_barrier(0); } while (0)

__global__ __launch_bounds__(64, 1) void scan_kernel(
    float* __restrict__ log_h, float* __restrict__ sign_h, float* __restrict__ h_lin,
    const float* __restrict__ log_r_h, const float* __restrict__ sign_r_h)
{
    __shared__ float ring[4][12][64];     // [slot][value][lane], 12 KB

    const int idx = blockIdx.x * 64 + threadIdx.x;
    const int ln  = threadIdx.x;
    const int d = idx & 1023;
    const float lrh = log_r_h[d];
    const float srh = sign_r_h[d];

    log_h[idx] = -40.0f;                  // row 0
    sign_h[idx] = 1.0f;

    float lhp = -40.0f;
    float shp = 1.0f;

    float Xa[4], Xli[4], Xsi[4], Xld[4], Xlm[4];

// Issue 12 fire-and-forget global->LDS loads for group GG into slot GG&3.
// Tail prefetch clamps the source group to 127 (dead slot, values unused).
#define ISSUE_LOADS(GG) do {                                             \
    const int _slot = (GG) & 3;                                          \
    const int _gc = ((GG) < 128) ? (GG) : 127;                           \
    const int _b = _gc * 4;                                              \
    _Pragma("unroll")                                                    \
    for (int u = 0; u < 4; ++u) {                                        \
        gl_lds(h_lin  + (size_t)(_b + u) * BD + idx,     &ring[_slot][u * 3 + 0][0]); \
        gl_lds(log_h  + (size_t)(_b + u + 1) * BD + idx, &ring[_slot][u * 3 + 1][0]); \
        gl_lds(sign_h + (size_t)(_b + u + 1) * BD + idx, &ring[_slot][u * 3 + 2][0]); \
    } } while (0)

// xform from LDS: bit-identical formulas to r8/r9 (passed).
#define XFORM(GG) do {                                                   \
    const int _slot = (GG) & 3;                                          \
    _Pragma("unroll")                                                    \
    for (int u = 0; u < 4; ++u) {                                        \
        const float araw = ring[_slot][u * 3 + 0][ln];                   \
        const float lin  = ring[_slot][u * 3 + 1][ln];                   \
        const float dr   = ring[_slot][u * 3 + 2][ln];                   \
        Xa[u] = __fadd_rn(1.0f, np_softplus(araw));                      \
        const float ax = fabsf(lin);                                     \
        Xli[u] = (ax > 1e-10f) ? np_logf(fmaxf(ax, 1e-10f)) : -40.0f;    \
        Xsi[u] = (lin < 0.0f) ? -1.0f : 1.0f;                            \
        const float e  = np_expf(-fabsf(dr));                            \
        const float l1 = np_log1pf(e);                                   \
        const float big = -__fadd_rn(fabsf(dr), l1);                     \
        const float sml = -l1;                                           \
        const float ld0 = (dr > 0.0f) ? sml : big;                       \
        const float lm0 = (dr > 0.0f) ? big : sml;                       \
        Xld[u] = (dr == 0.0f) ? -LOGE2F : ld0;                           \
        Xlm[u] = (dr == 0.0f) ? -LOGE2F : lm0;                           \
    } } while (0)

#define SERIAL4(GG) do {                                                 \
    _Pragma("unroll")                                                    \
    for (int u = 0; u < 4; ++u) {                                        \
        const int t = (GG) * 4 + u;                                      \
        const float log_rh  = __fadd_rn(lrh, lhp);                       \
        const float sign_rh = __fmul_rn(srh, shp);                       \
        float lv, sv;                                                    \
        np_sla(log_rh, sign_rh, Xli[u], Xsi[u], lv, sv);                 \
        const float tt = __fmul_rn(Xa[u], lv);                           \
        const float log_cand = -np_softplus(-tt);                        \
        float lhn, shn;                                                  \
        np_sla(__fadd_rn(Xlm[u], lhp), shp,                              \
               __fadd_rn(Xld[u], log_cand), sv, lhn, shn);               \
        const float res = __fmul_rn(shn, np_expf(fminf(lhn, 20.0f)));    \
        const float h = (lhn > -39.0f) ? res : 0.0f;                     \
        log_h[(t + 1) * BD + idx] = lhn;                                 \
        sign_h[(t + 1) * BD + idx] = shn;                                \
        h_lin[t * BD + idx] = h;                                         \
        lhp = lhn; shp = shn;                                            \
    } } while (0)

    // Prologue: slots 0,1 in flight.
    ISSUE_LOADS(0);
    ISSUE_LOADS(1);

    // Iteration 0 (peeled): only loads(1) are newer than loads(0).
    WAITVM(12);
    XFORM(0);
    SERIAL4(0);
    ISSUE_LOADS(2);

    // Steady state: newer-than-loads(g) = stores(g-1)[12] + loads(g+1)[12].
    for (int g = 1; g < 128; ++g) {
        WAITVM(24);
        XFORM(g);
        SERIAL4(g);
        ISSUE_LOADS(g + 2);
    }
#undef ISSUE_LOADS
#undef XFORM
#undef SERIAL4
}

// ===========================================================================
extern "C" void kernel_launch(void* const* d_in, const int* in_sizes, int n_in,
                              void* d_out, int out_size, void* d_ws, size_t ws_size,
                              hipStream_t stream) {
    const float* x        = (const float*)d_in[0];
    const float* W_x      = (const float*)d_in[1];
    const float* W_alpha  = (const float*)d_in[2];
    const float* W_delta  = (const float*)d_in[3];
    const float* b        = (const float*)d_in[4];
    const float* b_alpha  = (const float*)d_in[5];
    const float* b_delta  = (const float*)d_in[6];
    const float* log_r_h  = (const float*)d_in[7];
    const float* sign_r_h = (const float*)d_in[8];

    float* out    = (float*)d_out;
    float* log_h  = out;                            // [513, BD]
    float* sign_h = out + (size_t)513 * BD;         // [513, BD]
    float* h_lin  = out + (size_t)2 * 513 * BD;     // [512, BD]

    dim3 ggrid(GEMM_M / 64, NDIM / 64, 3);
    gemm_blas<<<ggrid, dim3(256), 0, stream>>>(
        x, W_alpha, W_x, W_delta, b_alpha, b, b_delta,
        h_lin, log_h + BD, sign_h + BD);

    scan_kernel<<<dim3(BD / 64), dim3(64), 0, stream>>>(
        log_h, sign_h, h_lin, log_r_h, sign_r_h);
}

// Round 12
// 1328.865 us; speedup vs baseline: 2.9305x; 1.2148x over previous
//
#include <hip/hip_runtime.h>
#include <math.h>

#define BD 16384            // B*D
#define TT 512
#define KDIM 1024
#define NDIM 1024
#define GEMM_M 8192
#define PANEL_Q 320         // OpenBLAS SGEMM_DEFAULT_Q (SKYLAKEX/COOPERLAKE AVX512 path)
#define LOGE2F 0.69314718246459960938f

// ===========================================================================
// Scan transcendentals: ROCm native f32 libm — FROZEN (r7-r11 passed).
// Compound arithmetic uses __fadd_rn/__fmul_rn/__fsub_rn to forbid FMA
// contraction. All value-producing formulas bit-identical to r9/r11.
// ===========================================================================
__device__ __forceinline__ float np_expf(float x)   { return expf(x); }
__device__ __forceinline__ float np_logf(float x)   { return logf(x); }
__device__ __forceinline__ float np_log1pf(float x) { return log1pf(x); }

__device__ __forceinline__ float np_softplus(float v) {
    const float e  = np_expf(-fabsf(v));
    const float l1 = np_log1pf(e);
    const float r  = __fadd_rn(fmaxf(v, 0.0f), l1);
    return (v == 0.0f) ? LOGE2F : r;      // npy_logaddexpf x==y special case
}

__device__ __forceinline__ void np_sla(float la, float sa, float lb, float sb,
                                       float& lo, float& so) {
    bool az = la <= -39.0f;                  // LOG_ZERO + 1
    bool bz = lb <= -39.0f;
    float mx = fmaxf(la, lb);
    float mn = fminf(la, lb);
    float diff = __fsub_rn(mn, mx);
    bool amax = la >= lb;
    float smax = amax ? sa : sb;
    float smin = amax ? sb : sa;
    bool same = __fmul_rn(smax, smin) > 0.0f;
    float ed = np_expf(diff);
    float ls  = __fadd_rn(mx, np_log1pf(ed));
    float lop = __fadd_rn(mx, np_log1pf(-fminf(ed, 0.9999f)));
    float l = same ? ls : lop;
    float s = smax;
    l = az ? lb : l;  s = az ? sb : s;
    bool bo = bz && !az;
    l = bo ? la : l;  s = bo ? sa : s;
    lo = l; so = s;
}

// ===========================================================================
// OpenBLAS-sgemm-exact NT-GEMM — FROZEN (r7-r11 passed): single-accumulator
// FMA chain, k ascending, Q=320 panels {320,320,320,64}, left-assoc fold,
// bias as separate f32 add. Tile 64x64, BK=16, 256 threads, 4x4 per thread.
// ===========================================================================
__global__ __launch_bounds__(256) void gemm_blas(
    const float* __restrict__ x,
    const float* __restrict__ Wa, const float* __restrict__ Wx, const float* __restrict__ Wd,
    const float* __restrict__ ba, const float* __restrict__ bx, const float* __restrict__ bd,
    float* __restrict__ out_a, float* __restrict__ out_x, float* __restrict__ out_d)
{
    const int z = blockIdx.z;
    const float* W    = (z == 0) ? Wa : (z == 1) ? Wx : Wd;
    const float* bias = (z == 0) ? ba : (z == 1) ? bx : bd;
    float* out        = (z == 0) ? out_a : (z == 1) ? out_x : out_d;

    const int m0 = blockIdx.x * 64;
    const int n0 = blockIdx.y * 64;

    __shared__ float As[16][68];   // [k in tile][m]
    __shared__ float Bs[16][68];   // [k in tile][n]

    const int tid = threadIdx.x;
    const int lr = tid >> 2;       // 0..63 staging row
    const int lc = tid & 3;        // float4 column
    const int ty = tid >> 4;       // 0..15 -> m = ty*4 + i
    const int tx = tid & 15;       // 0..15 -> n = tx*4 + j

    const float* Ap = x + (size_t)(m0 + lr) * KDIM + lc * 4;
    const float* Bp = W + (size_t)(n0 + lr) * KDIM + lc * 4;

    float4 fa = *(const float4*)Ap;
    float4 fb = *(const float4*)Bp;

    float tot[4][4];               // folded finished panels
    float acc[4][4];               // current panel FMA chain
    #pragma unroll
    for (int i = 0; i < 4; ++i)
        #pragma unroll
        for (int j = 0; j < 4; ++j) { tot[i][j] = 0.0f; acc[i][j] = 0.0f; }

    for (int kt = 0; kt < KDIM; kt += 16) {
        if (kt == PANEL_Q || kt == 2 * PANEL_Q || kt == 3 * PANEL_Q) {
            #pragma unroll
            for (int i = 0; i < 4; ++i)
                #pragma unroll
                for (int j = 0; j < 4; ++j) {
                    tot[i][j] = __fadd_rn(tot[i][j], acc[i][j]);  // C += panel
                    acc[i][j] = 0.0f;
                }
        }
        __syncthreads();
        {
            const float* pa = (const float*)&fa;
            const float* pb = (const float*)&fb;
            #pragma unroll
            for (int c = 0; c < 4; ++c) {
                As[lc * 4 + c][lr] = pa[c];
                Bs[lc * 4 + c][lr] = pb[c];
            }
        }
        __syncthreads();
        if (kt + 16 < KDIM) {
            fa = *(const float4*)(Ap + kt + 16);
            fb = *(const float4*)(Bp + kt + 16);
        }
        #pragma unroll
        for (int kk = 0; kk < 16; ++kk) {          // k strictly ascending
            const float4 a = *(const float4*)&As[kk][ty * 4];
            const float4 b = *(const float4*)&Bs[kk][tx * 4];
            const float av[4] = {a.x, a.y, a.z, a.w};
            const float bv[4] = {b.x, b.y, b.z, b.w};
            #pragma unroll
            for (int i = 0; i < 4; ++i)
                #pragma unroll
                for (int j = 0; j < 4; ++j)
                    acc[i][j] = __fmaf_rn(av[i], bv[j], acc[i][j]);
        }
    }
    #pragma unroll
    for (int i = 0; i < 4; ++i)                    // fold last (64-wide) panel
        #pragma unroll
        for (int j = 0; j < 4; ++j)
            tot[i][j] = __fadd_rn(tot[i][j], acc[i][j]);

    float bj[4];
    #pragma unroll
    for (int j = 0; j < 4; ++j) bj[j] = bias[n0 + tx * 4 + j];

    #pragma unroll
    for (int i = 0; i < 4; ++i) {
        float4 v;
        float* op = out + (size_t)(m0 + ty * 4 + i) * NDIM + n0 + tx * 4;
        v.x = __fadd_rn(tot[i][0], bj[0]);
        v.y = __fadd_rn(tot[i][1], bj[1]);
        v.z = __fadd_rn(tot[i][2], bj[2]);
        v.w = __fadd_rn(tot[i][3], bj[3]);
        *(float4*)op = v;
    }
}

// ===========================================================================
// f32 scan, T=512 as 128 groups of 4 — WAVE-SPECIALIZED, 3 waves/block over
// the same 64 chains:
//   wave 0 PRODUCER: global_load_lds raw ring (counted vmcnt(12) — its FIFO
//           holds only its own loads), xform (5 libm bodies/step), 2 groups
//           ahead, results to X-ring.
//   wave 1 CONSUMER: the true serial recurrence only (8 libm bodies/step),
//           LDS in / LDS out, zero global ops.
//   wave 2 WRITER:   epilogue expf + all global stores, 1 group behind.
// One __syncthreads per group; all ring slots (mod 4) have >=2-barrier
// separation producer->consumer->writer. Arithmetic bit-identical to r11.
// ===========================================================================
__device__ __forceinline__ void gl_lds(const float* g, float* l) {
    __builtin_amdgcn_global_load_lds(
        (const __attribute__((address_space(1))) void*)g,
        (__attribute__((address_space(3))) void*)l, 4, 0, 0);
}

#define WAITVM(N) do {                                                   \
    asm volatile("s_waitcnt vmcnt(" #N ")" ::: "memory");                \
    __builtin_amdgcn_sched_barrier(0); } while (0)

__global__ __launch_bounds__(192, 1) void scan_kernel(
    float* __restrict__ log_h, float* __restrict__ sign_h, float* __restrict__ h_lin,
    const float* __restrict__ log_r_h, const float* __restrict__ sign_r_h)
{
    __shared__ float Xr[4][5][4][64];   // [slot][a,li,si,ld,lm][u][lane]  20 KB
    __shared__ float Or[4][2][4][64];   // [slot][lhn,shn][u][lane]         8 KB
    __shared__ float Rr[4][12][64];     // raw ring (producer only)        12 KB

    const int wv = threadIdx.x >> 6;
    const int ln = threadIdx.x & 63;
    const int idx = blockIdx.x * 64 + ln;

// Producer: 12 fire-and-forget global->LDS loads of group GG into slot SL.
#define ISSUE_LOADS(GG, SL) do {                                         \
    const int _b = (GG) * 4;                                             \
    _Pragma("unroll")                                                    \
    for (int u = 0; u < 4; ++u) {                                        \
        gl_lds(h_lin  + (size_t)(_b + u) * BD + idx,     &Rr[SL][u * 3 + 0][0]); \
        gl_lds(log_h  + (size_t)(_b + u + 1) * BD + idx, &Rr[SL][u * 3 + 1][0]); \
        gl_lds(sign_h + (size_t)(_b + u + 1) * BD + idx, &Rr[SL][u * 3 + 2][0]); \
    } } while (0)

// Producer xform for group GG (raws in Rr[GG&3]) -> Xr[GG&3].
// Formulas bit-identical to r8-r11 (passed).
#define XFORM_TO(GG) do {                                                \
    const int _s = (GG) & 3;                                             \
    _Pragma("unroll")                                                    \
    for (int u = 0; u < 4; ++u) {                                        \
        const float araw = Rr[_s][u * 3 + 0][ln];                        \
        const float lin  = Rr[_s][u * 3 + 1][ln];                        \
        const float dr   = Rr[_s][u * 3 + 2][ln];                        \
        Xr[_s][0][u][ln] = __fadd_rn(1.0f, np_softplus(araw));           \
        const float ax = fabsf(lin);                                     \
        Xr[_s][1][u][ln] = (ax > 1e-10f) ? np_logf(fmaxf(ax, 1e-10f))    \
                                         : -40.0f;                       \
        Xr[_s][2][u][ln] = (lin < 0.0f) ? -1.0f : 1.0f;                  \
        const float e  = np_expf(-fabsf(dr));                            \
        const float l1 = np_log1pf(e);                                   \
        const float big = -__fadd_rn(fabsf(dr), l1);                     \
        const float sml = -l1;                                           \
        const float ld0 = (dr > 0.0f) ? sml : big;                       \
        const float lm0 = (dr > 0.0f) ? big : sml;                       \
        Xr[_s][3][u][ln] = (dr == 0.0f) ? -LOGE2F : ld0;                 \
        Xr[_s][4][u][ln] = (dr == 0.0f) ? -LOGE2F : lm0;                 \
    } } while (0)

// Writer: epilogue + all global stores for group GG (from Or[GG&3]).
#define WRITE_GROUP(GG) do {                                             \
    const int _s = (GG) & 3;                                             \
    _Pragma("unroll")                                                    \
    for (int u = 0; u < 4; ++u) {                                        \
        const int t = (GG) * 4 + u;                                      \
        const float lhn = Or[_s][0][u][ln];                              \
        const float shn = Or[_s][1][u][ln];                              \
        const float res = __fmul_rn(shn, np_expf(fminf(lhn, 20.0f)));    \
        const float h = (lhn > -39.0f) ? res : 0.0f;                     \
        log_h[(size_t)(t + 1) * BD + idx] = lhn;                         \
        sign_h[(size_t)(t + 1) * BD + idx] = shn;                        \
        h_lin[(size_t)t * BD + idx] = h;                                 \
    } } while (0)

    // ---- prologue ----
    float lrh = 0.0f, srh = 0.0f;
    if (wv == 1) {
        const int d = idx & 1023;
        lrh = log_r_h[d];
        srh = sign_r_h[d];
    } else if (wv == 0) {
        ISSUE_LOADS(0, 0);
        ISSUE_LOADS(1, 1);
        WAITVM(0);
        XFORM_TO(0);
        XFORM_TO(1);
        ISSUE_LOADS(2, 2);          // in flight across the barrier
    } else {
        log_h[idx] = -40.0f;        // row 0
        sign_h[idx] = 1.0f;
    }
    __syncthreads();

    float lhp = -40.0f, shp = 1.0f;

    for (int g = 0; g < 128; ++g) {
        if (wv == 0) {
            // FIFO before wait: loads(g+2)[12 old] | loads(g+3)[12 new]
            const int gl = (g + 3 < 128) ? g + 3 : 127;   // dead-slot clamp
            ISSUE_LOADS(gl, (g + 3) & 3);
            WAITVM(12);                                    // loads(g+2) done
            if (g + 2 < 128) XFORM_TO(g + 2);
        } else if (wv == 1) {
            const int s = g & 3;
            float xa[4], xli[4], xsi[4], xld[4], xlm[4];
            #pragma unroll
            for (int u = 0; u < 4; ++u) {
                xa[u]  = Xr[s][0][u][ln];
                xli[u] = Xr[s][1][u][ln];
                xsi[u] = Xr[s][2][u][ln];
                xld[u] = Xr[s][3][u][ln];
                xlm[u] = Xr[s][4][u][ln];
            }
            #pragma unroll
            for (int u = 0; u < 4; ++u) {       // serial chain (bit-frozen)
                const float log_rh  = __fadd_rn(lrh, lhp);
                const float sign_rh = __fmul_rn(srh, shp);
                float lv, sv;
                np_sla(log_rh, sign_rh, xli[u], xsi[u], lv, sv);
                const float tt = __fmul_rn(xa[u], lv);
                const float log_cand = -np_softplus(-tt);
                float lhn, shn;
                np_sla(__fadd_rn(xlm[u], lhp), shp,
                       __fadd_rn(xld[u], log_cand), sv, lhn, shn);
                Or[s][0][u][ln] = lhn;
                Or[s][1][u][ln] = shn;
                lhp = lhn; shp = shn;
            }
        } else {
            if (g > 0) WRITE_GROUP(g - 1);
        }
        __syncthreads();
    }
    if (wv == 2) WRITE_GROUP(127);   // last loop barrier orders Or[3]

#undef ISSUE_LOADS
#undef XFORM_TO
#undef WRITE_GROUP
}

// ===========================================================================
extern "C" void kernel_launch(void* const* d_in, const int* in_sizes, int n_in,
                              void* d_out, int out_size, void* d_ws, size_t ws_size,
                              hipStream_t stream) {
    const float* x        = (const float*)d_in[0];
    const float* W_x      = (const float*)d_in[1];
    const float* W_alpha  = (const float*)d_in[2];
    const float* W_delta  = (const float*)d_in[3];
    const float* b        = (const float*)d_in[4];
    const float* b_alpha  = (const float*)d_in[5];
    const float* b_delta  = (const float*)d_in[6];
    const float* log_r_h  = (const float*)d_in[7];
    const float* sign_r_h = (const float*)d_in[8];

    float* out    = (float*)d_out;
    float* log_h  = out;                            // [513, BD]
    float* sign_h = out + (size_t)513 * BD;         // [513, BD]
    float* h_lin  = out + (size_t)2 * 513 * BD;     // [512, BD]

    dim3 ggrid(GEMM_M / 64, NDIM / 64, 3);
    gemm_blas<<<ggrid, dim3(256), 0, stream>>>(
        x, W_alpha, W_x, W_delta, b_alpha, b, b_delta,
        h_lin, log_h + BD, sign_h + BD);

    scan_kernel<<<dim3(BD / 64), dim3(192), 0, stream>>>(
        log_h, sign_h, h_lin, log_r_h, sign_r_h);
}